// Round 2
// baseline (23056.856 us; speedup 1.0000x reference)
//
#include <hip/hip_runtime.h>
#include <hip/hip_bf16.h>

// Workspace layout (floats): [h1: N*32][h2: N*32][gbuf: 64*32][A: N*32][B: N*32]
// h1/h2/gbuf store non-negative float bit patterns (atomicMax on uint).

__global__ __launch_bounds__(256) void pre1_kernel(
    const float* __restrict__ pos, const float* __restrict__ w1a,
    const float* __restrict__ b1a, float* __restrict__ A, float* __restrict__ B, int N)
{
    int t = blockIdx.x * 256 + threadIdx.x;
    if (t >= N * 32) return;
    int n = t >> 5, c = t & 31;
    float px = pos[2 * n], py = pos[2 * n + 1];
    float w0 = w1a[c], w1 = w1a[32 + c], w2 = w1a[64 + c], w3 = w1a[96 + c];
    A[t] = fmaf(px, w0 + w2, fmaf(py, w1 + w3, b1a[c]));
    B[t] = -(px * w2 + py * w3);
}

__global__ __launch_bounds__(256) void pre2_kernel(
    const float* __restrict__ pos, const float* __restrict__ h1,
    const float* __restrict__ w2a, const float* __restrict__ b2a,
    float* __restrict__ C, float* __restrict__ D, int N)
{
    int t = blockIdx.x * 256 + threadIdx.x;
    if (t >= N * 32) return;
    int n = t >> 5, c = t & 31;
    float px = pos[2 * n], py = pos[2 * n + 1];
    float wx = w2a[32 * 32 + c], wy = w2a[33 * 32 + c];
    float s = fmaf(px, wx, fmaf(py, wy, b2a[c]));
    const float* hrow = h1 + n * 32;
#pragma unroll
    for (int k = 0; k < 32; ++k) s = fmaf(hrow[k], w2a[k * 32 + c], s);
    C[t] = s;
    D[t] = -(px * wx + py * wy);
}

// One thread per edge. Weights staged in LDS (broadcast reads).
// h[32] + m[32] kept in VGPRs; __launch_bounds__(256,2) allows up to 256 VGPRs
// so the compiler has no reason to spill.
__global__ __launch_bounds__(256, 2) void edge_mlp_kernel(
    const int* __restrict__ ei,            // [2, E]
    const float* __restrict__ Anode,       // [N,32] (src side, bias folded)
    const float* __restrict__ Bnode,       // [N,32] (dst side)
    const float* __restrict__ w,           // [32,32] row-major [k][c]
    const float* __restrict__ bias,        // [32]
    unsigned int* __restrict__ out,        // [N,32] uint-bits, 0-initialized
    int E)
{
    __shared__ float sw[32 * 32];
    __shared__ float sb[32];
    int tid = threadIdx.x;
#pragma unroll
    for (int i = 0; i < 4; ++i) sw[tid + 256 * i] = w[tid + 256 * i];
    if (tid < 32) sb[tid] = bias[tid];
    __syncthreads();

    int e = blockIdx.x * 256 + tid;
    if (e >= E) return;
    int src = ei[e];
    int dst = ei[E + e];

    const float4* ap = (const float4*)(Anode + (size_t)src * 32);
    const float4* bp = (const float4*)(Bnode + (size_t)dst * 32);

    float h[32];
#pragma unroll
    for (int q = 0; q < 8; ++q) {
        float4 a = ap[q];
        float4 b = bp[q];
        h[4 * q + 0] = fmaxf(a.x + b.x, 0.0f);
        h[4 * q + 1] = fmaxf(a.y + b.y, 0.0f);
        h[4 * q + 2] = fmaxf(a.z + b.z, 0.0f);
        h[4 * q + 3] = fmaxf(a.w + b.w, 0.0f);
    }

    float m[32];
    {
        const float4* bb = (const float4*)sb;
#pragma unroll
        for (int q = 0; q < 8; ++q) {
            float4 b = bb[q];
            m[4 * q + 0] = b.x; m[4 * q + 1] = b.y;
            m[4 * q + 2] = b.z; m[4 * q + 3] = b.w;
        }
    }

#pragma unroll
    for (int k = 0; k < 32; ++k) {
        float hk = h[k];
        const float4* wr = (const float4*)(sw + k * 32);
#pragma unroll
        for (int q = 0; q < 8; ++q) {
            float4 wv = wr[q];
            m[4 * q + 0] = fmaf(hk, wv.x, m[4 * q + 0]);
            m[4 * q + 1] = fmaf(hk, wv.y, m[4 * q + 1]);
            m[4 * q + 2] = fmaf(hk, wv.z, m[4 * q + 2]);
            m[4 * q + 3] = fmaf(hk, wv.w, m[4 * q + 3]);
        }
    }

    unsigned int base = (unsigned int)dst * 32u;
#pragma unroll
    for (int c = 0; c < 32; ++c) {
        if (m[c] > 0.0f) atomicMax(out + base + c, __float_as_uint(m[c]));
    }
}

__global__ __launch_bounds__(256) void pool_kernel(
    const float* __restrict__ h2, const int* __restrict__ batch,
    unsigned int* __restrict__ gbuf, int N)
{
    int t = blockIdx.x * 256 + threadIdx.x;
    if (t >= N * 32) return;
    int n = t >> 5, c = t & 31;
    float v = h2[t];
    if (v > 0.0f) atomicMax(gbuf + batch[n] * 32 + c, __float_as_uint(v));
}

__global__ __launch_bounds__(192) void out_kernel(
    const unsigned int* __restrict__ gbuf, const float* __restrict__ wc,
    const float* __restrict__ bc, float* __restrict__ out, int G)
{
    int t = threadIdx.x;
    if (t >= G * 3) return;
    int g = t / 3, j = t % 3;
    float s = bc[j];
#pragma unroll
    for (int c = 0; c < 32; ++c)
        s = fmaf(__uint_as_float(gbuf[g * 32 + c]), wc[c * 3 + j], s);
    out[t] = s;
}

extern "C" void kernel_launch(void* const* d_in, const int* in_sizes, int n_in,
                              void* d_out, int out_size, void* d_ws, size_t ws_size,
                              hipStream_t stream) {
    const float* pos = (const float*)d_in[0];
    const float* w1a = (const float*)d_in[1];
    const float* b1a = (const float*)d_in[2];
    const float* w1b = (const float*)d_in[3];
    const float* b1b = (const float*)d_in[4];
    const float* w2a = (const float*)d_in[5];
    const float* b2a = (const float*)d_in[6];
    const float* w2b = (const float*)d_in[7];
    const float* b2b = (const float*)d_in[8];
    const float* wc  = (const float*)d_in[9];
    const float* bc  = (const float*)d_in[10];
    const int* ei    = (const int*)d_in[11];
    const int* batch = (const int*)d_in[12];

    const int N = in_sizes[12];
    const int E = in_sizes[11] / 2;
    const int G = out_size / 3;
    const size_t NC = (size_t)N * 32;

    float* h1   = (float*)d_ws;
    float* h2   = h1 + NC;
    unsigned int* gbuf = (unsigned int*)(h2 + NC);
    float* A    = (float*)(gbuf + (size_t)G * 32);
    float* B    = A + NC;

    // zero h1, h2, gbuf in one shot (contiguous)
    hipMemsetAsync(d_ws, 0, (2 * NC + (size_t)G * 32) * sizeof(float), stream);

    int nThreads = (int)NC;
    int nBlocks = (nThreads + 255) / 256;
    int eBlocks = (E + 255) / 256;

    pre1_kernel<<<nBlocks, 256, 0, stream>>>(pos, w1a, b1a, A, B, N);
    edge_mlp_kernel<<<eBlocks, 256, 0, stream>>>(ei, A, B, w1b, b1b,
                                                 (unsigned int*)h1, E);
    pre2_kernel<<<nBlocks, 256, 0, stream>>>(pos, h1, w2a, b2a, A, B, N);
    edge_mlp_kernel<<<eBlocks, 256, 0, stream>>>(ei, A, B, w2b, b2b,
                                                 (unsigned int*)h2, E);
    pool_kernel<<<nBlocks, 256, 0, stream>>>(h2, batch, gbuf, N);
    out_kernel<<<1, 192, 0, stream>>>(gbuf, wc, bc, (float*)d_out, G);
}

// Round 3
// 1606.462 us; speedup vs baseline: 14.3526x; 14.3526x over previous
//
#include <hip/hip_runtime.h>
#include <hip/hip_bf16.h>

// Workspace layout (4B elems, all regions 16B-aligned):
// [deg:N][row_ptr:N+4][cursor:N][csr_src:E][A:N*32][B:N*32][h1:N*32][h2:N*32][gbuf:G*32]

__global__ __launch_bounds__(256) void pre1_kernel(
    const float* __restrict__ pos, const float* __restrict__ w1a,
    const float* __restrict__ b1a, float* __restrict__ A, float* __restrict__ B, int N)
{
    int t = blockIdx.x * 256 + threadIdx.x;
    if (t >= N * 32) return;
    int n = t >> 5, c = t & 31;
    float px = pos[2 * n], py = pos[2 * n + 1];
    float w0 = w1a[c], w1 = w1a[32 + c], w2 = w1a[64 + c], w3 = w1a[96 + c];
    A[t] = fmaf(px, w0 + w2, fmaf(py, w1 + w3, b1a[c]));
    B[t] = -(px * w2 + py * w3);
}

__global__ __launch_bounds__(256) void pre2_kernel(
    const float* __restrict__ pos, const float* __restrict__ h1,
    const float* __restrict__ w2a, const float* __restrict__ b2a,
    float* __restrict__ A, float* __restrict__ B, int N)
{
    int t = blockIdx.x * 256 + threadIdx.x;
    if (t >= N * 32) return;
    int n = t >> 5, c = t & 31;
    float px = pos[2 * n], py = pos[2 * n + 1];
    float wx = w2a[32 * 32 + c], wy = w2a[33 * 32 + c];
    float s = fmaf(px, wx, fmaf(py, wy, b2a[c]));
    const float* hrow = h1 + (size_t)n * 32;
#pragma unroll
    for (int k = 0; k < 32; ++k) s = fmaf(hrow[k], w2a[k * 32 + c], s);
    A[t] = s;
    B[t] = -(px * wx + py * wy);
}

__global__ __launch_bounds__(256) void hist_kernel(
    const int* __restrict__ ei, int* __restrict__ deg, int E)
{
    int e = blockIdx.x * 256 + threadIdx.x;
    if (e < E) atomicAdd(deg + ei[E + e], 1);
}

// Single-block scan: deg -> exclusive prefix (row_ptr and cursor), row_ptr[N]=E.
__global__ __launch_bounds__(1024) void scan_kernel(
    const int* __restrict__ deg, int* __restrict__ row_ptr,
    int* __restrict__ cursor, int N)
{
    __shared__ int wsum[16];
    __shared__ int woff[16];
    __shared__ int carry_s;
    int tid = threadIdx.x, lane = tid & 63, wv = tid >> 6;
    if (tid == 0) carry_s = 0;
    __syncthreads();
    for (int base = 0; base < N; base += 1024) {
        int i = base + tid;
        int v = (i < N) ? deg[i] : 0;
        int x = v;
#pragma unroll
        for (int off = 1; off < 64; off <<= 1) {
            int t = __shfl_up(x, off, 64);
            if (lane >= off) x += t;
        }
        if (lane == 63) wsum[wv] = x;
        __syncthreads();
        if (tid == 0) {
            int r = 0;
#pragma unroll
            for (int w = 0; w < 16; ++w) { woff[w] = r; r += wsum[w]; }
            wsum[0] = r;  // chunk total
        }
        __syncthreads();
        int c = carry_s;
        if (i < N) {
            int ex = c + woff[wv] + x - v;
            row_ptr[i] = ex;
            cursor[i] = ex;
        }
        int tot = wsum[0];
        __syncthreads();
        if (tid == 0) carry_s = c + tot;
        __syncthreads();
    }
    if (threadIdx.x == 0) row_ptr[N] = carry_s;
}

__global__ __launch_bounds__(256) void scatter_kernel(
    const int* __restrict__ ei, int* __restrict__ cursor,
    int* __restrict__ csr_src, int E)
{
    int e = blockIdx.x * 256 + threadIdx.x;
    if (e < E) {
        int pos = atomicAdd(cursor + ei[E + e], 1);
        csr_src[pos] = ei[e];
    }
}

// One thread per (node, 16-channel half). Iterates the node's in-edges from CSR,
// computes the 2-layer-MLP message fused in registers, max-reduces in registers.
// No atomics; h never materialized (consumed per-k). Weights wave-uniform -> s_load.
__global__ __launch_bounds__(256) void node_layer_kernel(
    const int* __restrict__ row_ptr, const int* __restrict__ csr_src,
    const float* __restrict__ A, const float* __restrict__ B,
    const float* __restrict__ w,      // [32k,32c] row-major
    const float* __restrict__ bias,   // [32]
    float* __restrict__ hout, int N)
{
    int n = blockIdx.x * 256 + threadIdx.x;
    int c0 = blockIdx.y * 16;   // wave-uniform channel base
    if (n >= N) return;
    int s = row_ptr[n], end = row_ptr[n + 1];
    const float4* Bq = (const float4*)(B + (size_t)n * 32);
    float macc[16];
#pragma unroll
    for (int j = 0; j < 16; ++j) macc[j] = 0.0f;

    for (; s < end; ++s) {
        int src = csr_src[s];
        const float4* Aq = (const float4*)(A + (size_t)src * 32);
        float m[16];
#pragma unroll
        for (int j = 0; j < 16; ++j) m[j] = bias[c0 + j];
#pragma unroll
        for (int q = 0; q < 8; ++q) {
            float4 a = Aq[q];
            float4 b = Bq[q];
            float h0 = fmaxf(a.x + b.x, 0.0f);
            float h1 = fmaxf(a.y + b.y, 0.0f);
            float h2 = fmaxf(a.z + b.z, 0.0f);
            float h3 = fmaxf(a.w + b.w, 0.0f);
            const float* w0 = w + (4 * q) * 32 + c0;
#pragma unroll
            for (int j = 0; j < 16; ++j) m[j] = fmaf(h0, w0[j], m[j]);
#pragma unroll
            for (int j = 0; j < 16; ++j) m[j] = fmaf(h1, w0[32 + j], m[j]);
#pragma unroll
            for (int j = 0; j < 16; ++j) m[j] = fmaf(h2, w0[64 + j], m[j]);
#pragma unroll
            for (int j = 0; j < 16; ++j) m[j] = fmaf(h3, w0[96 + j], m[j]);
        }
#pragma unroll
        for (int j = 0; j < 16; ++j) macc[j] = fmaxf(macc[j], m[j]);
    }

    float4* out4 = (float4*)(hout + (size_t)n * 32 + c0);
    out4[0] = make_float4(macc[0], macc[1], macc[2], macc[3]);
    out4[1] = make_float4(macc[4], macc[5], macc[6], macc[7]);
    out4[2] = make_float4(macc[8], macc[9], macc[10], macc[11]);
    out4[3] = make_float4(macc[12], macc[13], macc[14], macc[15]);
}

// batch is sorted: one block per graph, binary-search the node range, no atomics.
__global__ __launch_bounds__(256) void pool_kernel(
    const float* __restrict__ h2, const int* __restrict__ batch,
    float* __restrict__ gbuf, int N)
{
    int g = blockIdx.x;
    __shared__ int sbound[2];
    __shared__ float red[256];
    if (threadIdx.x < 2) {
        int target = g + (int)threadIdx.x;
        int lo = 0, hi = N;
        while (lo < hi) {
            int mid = (lo + hi) >> 1;
            if (batch[mid] < target) lo = mid + 1; else hi = mid;
        }
        sbound[threadIdx.x] = lo;
    }
    __syncthreads();
    int start = sbound[0], end = sbound[1];
    int c = threadIdx.x & 31, r = threadIdx.x >> 5;
    float mx = 0.0f;
    for (int n = start + r; n < end; n += 8)
        mx = fmaxf(mx, h2[(size_t)n * 32 + c]);
    red[threadIdx.x] = mx;
    __syncthreads();
    if (r < 4) red[threadIdx.x] = fmaxf(red[threadIdx.x], red[threadIdx.x + 128]);
    __syncthreads();
    if (r < 2) red[threadIdx.x] = fmaxf(red[threadIdx.x], red[threadIdx.x + 64]);
    __syncthreads();
    if (r == 0) gbuf[g * 32 + c] = fmaxf(red[threadIdx.x], red[threadIdx.x + 32]);
}

__global__ __launch_bounds__(192) void out_kernel(
    const float* __restrict__ gbuf, const float* __restrict__ wc,
    const float* __restrict__ bc, float* __restrict__ out, int G)
{
    int t = threadIdx.x;
    if (t >= G * 3) return;
    int g = t / 3, j = t % 3;
    float s = bc[j];
#pragma unroll
    for (int c = 0; c < 32; ++c)
        s = fmaf(gbuf[g * 32 + c], wc[c * 3 + j], s);
    out[t] = s;
}

extern "C" void kernel_launch(void* const* d_in, const int* in_sizes, int n_in,
                              void* d_out, int out_size, void* d_ws, size_t ws_size,
                              hipStream_t stream) {
    const float* pos = (const float*)d_in[0];
    const float* w1a = (const float*)d_in[1];
    const float* b1a = (const float*)d_in[2];
    const float* w1b = (const float*)d_in[3];
    const float* b1b = (const float*)d_in[4];
    const float* w2a = (const float*)d_in[5];
    const float* b2a = (const float*)d_in[6];
    const float* w2b = (const float*)d_in[7];
    const float* b2b = (const float*)d_in[8];
    const float* wc  = (const float*)d_in[9];
    const float* bc  = (const float*)d_in[10];
    const int* ei    = (const int*)d_in[11];
    const int* batch = (const int*)d_in[12];

    const int N = in_sizes[12];
    const int E = in_sizes[11] / 2;
    const int G = out_size / 3;
    const size_t NC = (size_t)N * 32;

    int* deg     = (int*)d_ws;
    int* row_ptr = deg + N;            // N+1 used, N+4 reserved
    int* cursor  = row_ptr + (N + 4);
    int* csr_src = cursor + N;
    float* A     = (float*)(csr_src + E);
    float* B     = A + NC;
    float* h1    = B + NC;
    float* h2    = h1 + NC;
    float* gbuf  = h2 + NC;

    hipMemsetAsync(deg, 0, (size_t)N * sizeof(int), stream);

    int eBlocks = (E + 255) / 256;
    int ncBlocks = ((int)NC + 255) / 256;
    int nBlocks = (N + 255) / 256;

    hist_kernel<<<eBlocks, 256, 0, stream>>>(ei, deg, E);
    scan_kernel<<<1, 1024, 0, stream>>>(deg, row_ptr, cursor, N);
    scatter_kernel<<<eBlocks, 256, 0, stream>>>(ei, cursor, csr_src, E);

    pre1_kernel<<<ncBlocks, 256, 0, stream>>>(pos, w1a, b1a, A, B, N);
    node_layer_kernel<<<dim3(nBlocks, 2), 256, 0, stream>>>(
        row_ptr, csr_src, A, B, w1b, b1b, h1, N);
    pre2_kernel<<<ncBlocks, 256, 0, stream>>>(pos, h1, w2a, b2a, A, B, N);
    node_layer_kernel<<<dim3(nBlocks, 2), 256, 0, stream>>>(
        row_ptr, csr_src, A, B, w2b, b2b, h2, N);
    pool_kernel<<<G, 256, 0, stream>>>(h2, batch, gbuf, N);
    out_kernel<<<1, 192, 0, stream>>>(gbuf, wc, bc, (float*)d_out, G);
}